// Round 1
// baseline (666.616 us; speedup 1.0000x reference)
//
#include <hip/hip_runtime.h>
#include <math.h>

#define D 128

// Monotonic float->uint encoding: preserves total order (non-NaN) under
// unsigned comparison. enc(-inf) = 0x007FFFFF.
__device__ __forceinline__ unsigned enc_f32(float f) {
    unsigned b = __float_as_uint(f);
    return b ^ ((unsigned)((int)b >> 31) | 0x80000000u);
}

__global__ void init_out_kernel(unsigned* __restrict__ out, int n) {
    int i = blockIdx.x * blockDim.x + threadIdx.x;
    int stride = gridDim.x * blockDim.x;
    for (; i < n; i += stride) out[i] = 0x007FFFFFu;  // enc(-inf)
}

__global__ void decode_out_kernel(unsigned* __restrict__ out, int n) {
    int i = blockIdx.x * blockDim.x + threadIdx.x;
    int stride = gridDim.x * blockDim.x;
    for (; i < n; i += stride) {
        unsigned k = out[i];
        out[i] = (k & 0x80000000u) ? (k ^ 0x80000000u) : ~k;
    }
}

// One wave (64 lanes) per 64-row chunk. lane owns features [2*lane, 2*lane+1]
// as a float2 -> each row is one fully-coalesced 512B wave load.
// Sorted batch => runs; flush running max with uint atomicMax at run ends.
__launch_bounds__(256, 8)
__global__ void seg_max_kernel(const float2* __restrict__ x,
                               const int* __restrict__ batch,
                               unsigned* __restrict__ out,
                               int n) {
    const int wave = (int)((blockIdx.x * blockDim.x + threadIdx.x) >> 6);
    const int lane = (int)(threadIdx.x & 63);

    long r0 = (long)wave * 64;
    if (r0 >= n) return;
    long r1 = r0 + 64;
    if (r1 > n) r1 = n;
    const int nr = (int)(r1 - r0);

    // Coalesced preload of this chunk's 64 batch ids (one load per lane).
    long bidx = r0 + lane;
    if (bidx > (long)n - 1) bidx = (long)n - 1;
    int bl = batch[bidx];

    int cur = __shfl(bl, 0);
    const float NEG_INF = -__builtin_inff();
    float2 m = make_float2(NEG_INF, NEG_INF);

    const float2* xp = x + r0 * (D / 2) + lane;

    #pragma unroll 4
    for (int r = 0; r < nr; ++r) {
        int b = __shfl(bl, r);
        if (b != cur) {  // runtime wave-uniform
            unsigned* o = out + (size_t)cur * D + (size_t)lane * 2;
            atomicMax(o,     enc_f32(m.x));
            atomicMax(o + 1, enc_f32(m.y));
            cur = b;
            m.x = NEG_INF;
            m.y = NEG_INF;
        }
        float2 v = xp[(size_t)r * (D / 2)];
        m.x = fmaxf(m.x, v.x);
        m.y = fmaxf(m.y, v.y);
    }
    unsigned* o = out + (size_t)cur * D + (size_t)lane * 2;
    atomicMax(o,     enc_f32(m.x));
    atomicMax(o + 1, enc_f32(m.y));
}

extern "C" void kernel_launch(void* const* d_in, const int* in_sizes, int n_in,
                              void* d_out, int out_size, void* d_ws, size_t ws_size,
                              hipStream_t stream) {
    const float2* x = (const float2*)d_in[0];
    const int* batch = (const int*)d_in[1];
    unsigned* out_u = (unsigned*)d_out;

    const int n = in_sizes[1];          // number of rows (atoms)
    const int out_elems = out_size;     // B * D

    // 1) init output to enc(-inf)
    {
        int blocks = 1024;
        init_out_kernel<<<blocks, 256, 0, stream>>>(out_u, out_elems);
    }

    // 2) segmented max
    {
        int waves = (n + 63) / 64;
        int blocks = (waves + 3) / 4;  // 256 threads = 4 waves per block
        seg_max_kernel<<<blocks, 256, 0, stream>>>(x, batch, out_u, n);
    }

    // 3) decode keys back to floats (in-place; empty segments -> -inf)
    {
        int blocks = 1024;
        decode_out_kernel<<<blocks, 256, 0, stream>>>(out_u, out_elems);
    }
}

// Round 6
// 664.673 us; speedup vs baseline: 1.0029x; 1.0029x over previous
//
#include <hip/hip_runtime.h>
#include <math.h>

#define D 128

// Monotonic float->uint encoding: preserves total order (non-NaN) under
// unsigned comparison. enc(-inf) = 0x007FFFFF.
__device__ __forceinline__ unsigned enc_f32(float f) {
    unsigned b = __float_as_uint(f);
    return b ^ ((unsigned)((int)b >> 31) | 0x80000000u);
}

__global__ void init_out_kernel(unsigned* __restrict__ out, int n) {
    int i = blockIdx.x * blockDim.x + threadIdx.x;
    int stride = gridDim.x * blockDim.x;
    for (; i < n; i += stride) out[i] = 0x007FFFFFu;  // enc(-inf)
}

__global__ void decode_out_kernel(unsigned* __restrict__ out, int n) {
    int i = blockIdx.x * blockDim.x + threadIdx.x;
    int stride = gridDim.x * blockDim.x;
    for (; i < n; i += stride) {
        unsigned k = out[i];
        out[i] = (k & 0x80000000u) ? (k ^ 0x80000000u) : ~k;
    }
}

// One wave (64 lanes) per 64-row chunk; lane owns features [2*lane, 2*lane+1].
// Sorted batch => contiguous runs. Per chunk: build boundary bitmask once
// (ballot), then per run execute a branch-free max loop with 8 loads in
// flight, and flush with 2 uint atomicMax per lane per run.
__launch_bounds__(256, 8)
__global__ void seg_max_kernel(const float2* __restrict__ x,
                               const int* __restrict__ batch,
                               unsigned* __restrict__ out,
                               int n) {
    const int wave = (int)((blockIdx.x * blockDim.x + threadIdx.x) >> 6);
    const int lane = (int)(threadIdx.x & 63);

    long r0 = (long)wave * 64;
    if (r0 >= n) return;
    long rem = (long)n - r0;
    const int nr = (rem < 64) ? (int)rem : 64;

    // Coalesced preload of this chunk's batch ids (clamped; clamped lanes
    // replicate the last valid id so they create no boundary bits).
    long bidx = r0 + lane;
    if (bidx > (long)n - 1) bidx = (long)n - 1;
    const int bl = batch[bidx];
    const int blp = __shfl_up(bl, 1);
    const unsigned long long bmask = __ballot(lane > 0 && bl != blp);

    const float NEG_INF = -__builtin_inff();
    const float2* xp = x + r0 * (D / 2) + lane;

    int s = 0;
    while (s < nr) {
        // End of this run: next boundary bit above s, else nr.
        unsigned long long m2 = (s < 63) ? ((bmask >> (s + 1)) << (s + 1)) : 0ULL;
        const int e = m2 ? __builtin_ctzll(m2) : nr;
        const int seg = __shfl(bl, s);
        const int len = e - s;
        const float2* rp = xp + (size_t)s * (D / 2);

        float2 m = make_float2(NEG_INF, NEG_INF);
        int r = 0;
        // 8 independent loads in flight per iteration.
        for (; r + 8 <= len; r += 8) {
            float2 v0 = rp[(size_t)(r + 0) * (D / 2)];
            float2 v1 = rp[(size_t)(r + 1) * (D / 2)];
            float2 v2 = rp[(size_t)(r + 2) * (D / 2)];
            float2 v3 = rp[(size_t)(r + 3) * (D / 2)];
            float2 v4 = rp[(size_t)(r + 4) * (D / 2)];
            float2 v5 = rp[(size_t)(r + 5) * (D / 2)];
            float2 v6 = rp[(size_t)(r + 6) * (D / 2)];
            float2 v7 = rp[(size_t)(r + 7) * (D / 2)];
            m.x = fmaxf(m.x, fmaxf(fmaxf(v0.x, v1.x), fmaxf(v2.x, v3.x)));
            m.y = fmaxf(m.y, fmaxf(fmaxf(v0.y, v1.y), fmaxf(v2.y, v3.y)));
            m.x = fmaxf(m.x, fmaxf(fmaxf(v4.x, v5.x), fmaxf(v6.x, v7.x)));
            m.y = fmaxf(m.y, fmaxf(fmaxf(v4.y, v5.y), fmaxf(v6.y, v7.y)));
        }
        for (; r < len; ++r) {
            float2 v = rp[(size_t)r * (D / 2)];
            m.x = fmaxf(m.x, v.x);
            m.y = fmaxf(m.y, v.y);
        }

        unsigned* o = out + (size_t)seg * D + (size_t)lane * 2;
        atomicMax(o,     enc_f32(m.x));
        atomicMax(o + 1, enc_f32(m.y));
        s = e;
    }
}

extern "C" void kernel_launch(void* const* d_in, const int* in_sizes, int n_in,
                              void* d_out, int out_size, void* d_ws, size_t ws_size,
                              hipStream_t stream) {
    const float2* x = (const float2*)d_in[0];
    const int* batch = (const int*)d_in[1];
    unsigned* out_u = (unsigned*)d_out;

    const int n = in_sizes[1];          // number of rows (atoms)
    const int out_elems = out_size;     // B * D

    // 1) init output to enc(-inf)
    init_out_kernel<<<1024, 256, 0, stream>>>(out_u, out_elems);

    // 2) segmented max over sorted batch
    {
        int waves = (n + 63) / 64;
        int blocks = (waves + 3) / 4;   // 256 threads = 4 waves per block
        seg_max_kernel<<<blocks, 256, 0, stream>>>(x, batch, out_u, n);
    }

    // 3) decode keys back to floats (in-place; empty segments -> -inf)
    decode_out_kernel<<<1024, 256, 0, stream>>>(out_u, out_elems);
}